// Round 1
// baseline (1161.842 us; speedup 1.0000x reference)
//
#include <hip/hip_runtime.h>
#include <hip/hip_bf16.h>

#define NT 557056
typedef __hip_bfloat16 bf16;

__device__ __forceinline__ float b2f(bf16 v){ return __bfloat162float(v); }
__device__ __forceinline__ bf16  f2b(float v){ return __float2bfloat16(v); }

// ---------------------------------------------------------------------------
// K1: per-position MLPs m1 = MLP(x; w_m1), m2 = MLP(x; w_m2)  (2 layers each,
// Linear(64->64)+ReLU). Writes channel-major bf16 planes m1t/m2t: [c][p].
// One thread = one position. x row in registers; inter-layer activation in a
// private LDS column (constant-indexed reads); weights are thread-uniform
// addresses -> scalar loads (broadcast).
// ---------------------------------------------------------------------------
__global__ __launch_bounds__(256) void k1_mlp(
    const float* __restrict__ x,
    const float* __restrict__ w_m1, const float* __restrict__ b_m1,
    const float* __restrict__ w_m2, const float* __restrict__ b_m2,
    bf16* __restrict__ m1t, bf16* __restrict__ m2t)
{
  __shared__ bf16 t_lds[64][256];
  const int tid = threadIdx.x;
  const size_t p = (size_t)blockIdx.x * 256 + tid;

  float xr[64];
  const float4* x4 = (const float4*)(x + p * 64);
  #pragma unroll
  for (int i = 0; i < 16; ++i) {
    float4 v = x4[i];
    xr[4*i+0]=v.x; xr[4*i+1]=v.y; xr[4*i+2]=v.z; xr[4*i+3]=v.w;
  }

  for (int m = 0; m < 2; ++m) {
    const float* w  = m ? w_m2 : w_m1;
    const float* b  = m ? b_m2 : b_m1;
    bf16* outp      = m ? m2t  : m1t;

    // layer 0: xr -> t_lds (relu)
    for (int oc = 0; oc < 8; ++oc) {
      float acc[8];
      #pragma unroll
      for (int oo = 0; oo < 8; ++oo) acc[oo] = b[oc*8+oo];
      #pragma unroll
      for (int i4 = 0; i4 < 16; ++i4) {
        const float a0 = xr[4*i4+0], a1 = xr[4*i4+1], a2 = xr[4*i4+2], a3 = xr[4*i4+3];
        #pragma unroll
        for (int oo = 0; oo < 8; ++oo) {
          const float4 wv = *(const float4*)(w + (oc*8+oo)*64 + 4*i4);
          acc[oo] = fmaf(a0, wv.x, fmaf(a1, wv.y, fmaf(a2, wv.z, fmaf(a3, wv.w, acc[oo]))));
        }
      }
      #pragma unroll
      for (int oo = 0; oo < 8; ++oo)
        t_lds[oc*8+oo][tid] = f2b(fmaxf(acc[oo], 0.f));
    }
    // layer 1: t_lds -> global bf16 (relu), channel-major
    const float* w1 = w + 4096;
    const float* b1 = b + 64;
    for (int oc = 0; oc < 8; ++oc) {
      float acc[8];
      #pragma unroll
      for (int oo = 0; oo < 8; ++oo) acc[oo] = b1[oc*8+oo];
      #pragma unroll
      for (int i = 0; i < 64; ++i) {
        const float tv = b2f(t_lds[i][tid]);
        #pragma unroll
        for (int oo = 0; oo < 8; ++oo)
          acc[oo] = fmaf(tv, w1[(oc*8+oo)*64 + i], acc[oo]);
      }
      #pragma unroll
      for (int oo = 0; oo < 8; ++oo)
        outp[(size_t)(oc*8+oo) * NT + p] = f2b(fmaxf(acc[oo], 0.f));
    }
  }
}

// ---------------------------------------------------------------------------
// K2: per (block, channel) spatial matmul H = M1 @ M2 (n x n). Planes are
// contiguous bf16. Output written bf16 over the m1t storage (safe alias: the
// workgroup loads its whole plane to LDS before writing).
// ---------------------------------------------------------------------------
template<int N>
__global__ __launch_bounds__(256) void k2_spatial(
    const bf16* __restrict__ m1t, const bf16* __restrict__ m2t,
    bf16* __restrict__ ht, int off)
{
  constexpr int T = N / 16;
  __shared__ float A[N][N+1];
  __shared__ float B[N][N+1];
  const int b = blockIdx.x >> 6;
  const int c = blockIdx.x & 63;
  const size_t pbase = (size_t)c * NT + (size_t)off + (size_t)b * N * N;
  const int tid = threadIdx.x;

  for (int t = tid; t < N*N; t += 256) {
    A[t / N][t % N] = b2f(m1t[pbase + t]);
    B[t / N][t % N] = b2f(m2t[pbase + t]);
  }
  __syncthreads();

  const int ti = tid >> 4, tk = tid & 15;
  float acc[T][T];
  #pragma unroll
  for (int ii = 0; ii < T; ++ii)
    #pragma unroll
    for (int kk = 0; kk < T; ++kk) acc[ii][kk] = 0.f;

  for (int j = 0; j < N; ++j) {
    float av[T], bv[T];
    #pragma unroll
    for (int ii = 0; ii < T; ++ii) av[ii] = A[ti*T+ii][j];
    #pragma unroll
    for (int kk = 0; kk < T; ++kk) bv[kk] = B[j][tk*T+kk];
    #pragma unroll
    for (int ii = 0; ii < T; ++ii)
      #pragma unroll
      for (int kk = 0; kk < T; ++kk)
        acc[ii][kk] = fmaf(av[ii], bv[kk], acc[ii][kk]);
  }

  #pragma unroll
  for (int ii = 0; ii < T; ++ii) {
    const int i = ti*T + ii;
    #pragma unroll
    for (int kk = 0; kk < T; ++kk) {
      const int k = tk*T + kk;
      ht[pbase + i*N + k] = f2b(acc[ii][kk]);
    }
  }
}

// ---------------------------------------------------------------------------
// K3: hs2 = h + x@Wskip^T + bskip; u1 = relu(bn1(hs2@Wu1^T+bu1));
//     u2 = relu(bn2(u1@Wu2^T+bu2)); out = u2 + hs2.
// One thread = one position; hs2/u1 in private bf16 LDS columns.
// ---------------------------------------------------------------------------
__global__ __launch_bounds__(256) void k3_update(
    const float* __restrict__ x, const bf16* __restrict__ ht,
    const float* __restrict__ Wskip, const float* __restrict__ bskip,
    const float* __restrict__ Wu1, const float* __restrict__ bu1,
    const float* __restrict__ g1, const float* __restrict__ be1,
    const float* __restrict__ rm1, const float* __restrict__ rv1,
    const float* __restrict__ Wu2, const float* __restrict__ bu2,
    const float* __restrict__ g2, const float* __restrict__ be2,
    const float* __restrict__ rm2, const float* __restrict__ rv2,
    float* __restrict__ out)
{
  __shared__ bf16 hs2_lds[64][256];
  __shared__ bf16 u1_lds[64][256];
  const int tid = threadIdx.x;
  const size_t p = (size_t)blockIdx.x * 256 + tid;

  float xr[64];
  const float4* x4 = (const float4*)(x + p * 64);
  #pragma unroll
  for (int i = 0; i < 16; ++i) {
    float4 v = x4[i];
    xr[4*i+0]=v.x; xr[4*i+1]=v.y; xr[4*i+2]=v.z; xr[4*i+3]=v.w;
  }

  // skip + h -> hs2
  for (int oc = 0; oc < 8; ++oc) {
    float acc[8];
    #pragma unroll
    for (int oo = 0; oo < 8; ++oo) acc[oo] = bskip[oc*8+oo];
    #pragma unroll
    for (int i4 = 0; i4 < 16; ++i4) {
      const float a0 = xr[4*i4+0], a1 = xr[4*i4+1], a2 = xr[4*i4+2], a3 = xr[4*i4+3];
      #pragma unroll
      for (int oo = 0; oo < 8; ++oo) {
        const float4 wv = *(const float4*)(Wskip + (oc*8+oo)*64 + 4*i4);
        acc[oo] = fmaf(a0, wv.x, fmaf(a1, wv.y, fmaf(a2, wv.z, fmaf(a3, wv.w, acc[oo]))));
      }
    }
    #pragma unroll
    for (int oo = 0; oo < 8; ++oo) {
      const int o = oc*8 + oo;
      const float hs2 = acc[oo] + b2f(ht[(size_t)o * NT + p]);
      hs2_lds[o][tid] = f2b(hs2);
    }
  }

  // u1 = relu(bn1(hs2 @ Wu1^T + bu1))
  for (int oc = 0; oc < 8; ++oc) {
    float acc[8];
    #pragma unroll
    for (int oo = 0; oo < 8; ++oo) acc[oo] = bu1[oc*8+oo];
    #pragma unroll
    for (int i = 0; i < 64; ++i) {
      const float hv = b2f(hs2_lds[i][tid]);
      #pragma unroll
      for (int oo = 0; oo < 8; ++oo)
        acc[oo] = fmaf(hv, Wu1[(oc*8+oo)*64 + i], acc[oo]);
    }
    #pragma unroll
    for (int oo = 0; oo < 8; ++oo) {
      const int o = oc*8 + oo;
      const float sc = g1[o] * rsqrtf(rv1[o] + 1e-5f);
      const float sh = be1[o] - rm1[o] * sc;
      u1_lds[o][tid] = f2b(fmaxf(fmaf(acc[oo], sc, sh), 0.f));
    }
  }

  // u2 + residual -> out
  for (int oc = 0; oc < 8; ++oc) {
    float acc[8];
    #pragma unroll
    for (int oo = 0; oo < 8; ++oo) acc[oo] = bu2[oc*8+oo];
    #pragma unroll
    for (int i = 0; i < 64; ++i) {
      const float uv = b2f(u1_lds[i][tid]);
      #pragma unroll
      for (int oo = 0; oo < 8; ++oo)
        acc[oo] = fmaf(uv, Wu2[(oc*8+oo)*64 + i], acc[oo]);
    }
    float res[8];
    #pragma unroll
    for (int oo = 0; oo < 8; ++oo) {
      const int o = oc*8 + oo;
      const float sc = g2[o] * rsqrtf(rv2[o] + 1e-5f);
      const float sh = be2[o] - rm2[o] * sc;
      res[oo] = fmaxf(fmaf(acc[oo], sc, sh), 0.f) + b2f(hs2_lds[o][tid]);
    }
    float4* o4 = (float4*)(out + p * 64);
    o4[oc*2+0] = make_float4(res[0], res[1], res[2], res[3]);
    o4[oc*2+1] = make_float4(res[4], res[5], res[6], res[7]);
  }
}

// ---------------------------------------------------------------------------
extern "C" void kernel_launch(void* const* d_in, const int* in_sizes, int n_in,
                              void* d_out, int out_size, void* d_ws, size_t ws_size,
                              hipStream_t stream) {
  const float* x     = (const float*)d_in[0];
  const float* w_m1  = (const float*)d_in[1];
  const float* b_m1  = (const float*)d_in[2];
  const float* w_m2  = (const float*)d_in[3];
  const float* b_m2  = (const float*)d_in[4];
  const float* Wskip = (const float*)d_in[5];
  const float* bskip = (const float*)d_in[6];
  const float* Wu1   = (const float*)d_in[7];
  const float* bu1   = (const float*)d_in[8];
  const float* g1    = (const float*)d_in[9];
  const float* be1   = (const float*)d_in[10];
  const float* rm1   = (const float*)d_in[11];
  const float* rv1   = (const float*)d_in[12];
  const float* Wu2   = (const float*)d_in[13];
  const float* bu2   = (const float*)d_in[14];
  const float* g2    = (const float*)d_in[15];
  const float* be2   = (const float*)d_in[16];
  const float* rm2   = (const float*)d_in[17];
  const float* rv2   = (const float*)d_in[18];
  float* out = (float*)d_out;

  // ws layout: m1t [64*NT bf16] | m2t [64*NT bf16]; ht aliases m1t (K2's
  // workgroup fully loads its plane to LDS before overwriting it).
  bf16* m1t = (bf16*)d_ws;
  bf16* m2t = m1t + (size_t)64 * NT;
  bf16* ht  = m1t;

  k1_mlp<<<NT/256, 256, 0, stream>>>(x, w_m1, b_m1, w_m2, b_m2, m1t, m2t);

  // regions: (bnum, n, off): (128,32,0) (64,48,131072) (32,64,278528) (16,96,409600)
  k2_spatial<32><<<128*64, 256, 0, stream>>>(m1t, m2t, ht, 0);
  k2_spatial<48><<< 64*64, 256, 0, stream>>>(m1t, m2t, ht, 131072);
  k2_spatial<64><<< 32*64, 256, 0, stream>>>(m1t, m2t, ht, 278528);
  k2_spatial<96><<< 16*64, 256, 0, stream>>>(m1t, m2t, ht, 409600);

  k3_update<<<NT/256, 256, 0, stream>>>(x, ht, Wskip, bskip,
                                        Wu1, bu1, g1, be1, rm1, rv1,
                                        Wu2, bu2, g2, be2, rm2, rv2, out);
}

// Round 2
// 617.187 us; speedup vs baseline: 1.8825x; 1.8825x over previous
//
#include <hip/hip_runtime.h>
#include <hip/hip_bf16.h>

#define NT 557056
typedef __hip_bfloat16 bf16;
typedef __attribute__((ext_vector_type(8))) short short8;
typedef __attribute__((ext_vector_type(4))) short short4v;
typedef __attribute__((ext_vector_type(4))) float f32x4;

__device__ __forceinline__ float b2f(bf16 v){ return __bfloat162float(v); }
__device__ __forceinline__ short f2bs(float f){ bf16 h = __float2bfloat16(f); return *(short*)&h; }
__device__ __forceinline__ float s2f(short s){ bf16 h = *(bf16*)&s; return __bfloat162float(h); }

// Load 8 consecutive f32 at p -> bf16x8 fragment.
// A-frag role: lane holds A[row=l&15][k=(l>>4)*8+j] (transposed GEMMs);
// B-frag role: lane holds B[k=(l>>4)*8+j][col=l&15] (normal GEMMs).
__device__ __forceinline__ short8 ldfrag(const float* __restrict__ p){
  float4 a = *(const float4*)p;
  float4 b = *(const float4*)(p + 4);
  short8 r;
  r[0]=f2bs(a.x); r[1]=f2bs(a.y); r[2]=f2bs(a.z); r[3]=f2bs(a.w);
  r[4]=f2bs(b.x); r[5]=f2bs(b.y); r[6]=f2bs(b.z); r[7]=f2bs(b.w);
  return r;
}
#define MFMA(a,b,c) __builtin_amdgcn_mfma_f32_16x16x32_bf16(a, b, c, 0, 0, 0)

#define LS 72  // LDS row stride in shorts: 144B rows, 16B aligned

// ---------------------------------------------------------------------------
// K1: m1 = MLP(x; w_m1), m2 = MLP(x; w_m2). Per wave: 32 positions.
// ---------------------------------------------------------------------------
__global__ __launch_bounds__(256) void k1_mlp(
    const float* __restrict__ x,
    const float* __restrict__ w_m1, const float* __restrict__ b_m1,
    const float* __restrict__ w_m2, const float* __restrict__ b_m2,
    bf16* __restrict__ m1t, bf16* __restrict__ m2t)
{
  __shared__ short yL[4][32][LS];
  const int tid = threadIdx.x;
  const int wv = tid >> 6, lane = tid & 63, r = lane & 15, g = lane >> 4;
  const int pbase = blockIdx.x * 128 + wv * 32;

  short8 xf[2][2];
  #pragma unroll
  for (int t = 0; t < 2; ++t)
    #pragma unroll
    for (int s = 0; s < 2; ++s)
      xf[t][s] = ldfrag(x + (size_t)(pbase + t*16 + r) * 64 + s*32 + g*8);

  for (int m = 0; m < 2; ++m) {
    const float* w0 = m ? w_m2 : w_m1;
    const float* b0 = m ? b_m2 : b_m1;
    const float* w1 = w0 + 4096;
    const float* b1 = b0 + 64;
    bf16* outp = m ? m2t : m1t;

    // L0 transposed: rows = out-ch, cols = pos
    f32x4 acc[4][2];
    #pragma unroll
    for (int cb = 0; cb < 4; ++cb) {
      f32x4 bi = *(const f32x4*)(b0 + cb*16 + 4*g);
      acc[cb][0] = bi; acc[cb][1] = bi;
    }
    #pragma unroll
    for (int cb = 0; cb < 4; ++cb)
      #pragma unroll
      for (int s = 0; s < 2; ++s) {
        short8 wf = ldfrag(w0 + (cb*16 + r)*64 + s*32 + g*8);
        acc[cb][0] = MFMA(wf, xf[0][s], acc[cb][0]);
        acc[cb][1] = MFMA(wf, xf[1][s], acc[cb][1]);
      }
    __syncthreads();
    #pragma unroll
    for (int cb = 0; cb < 4; ++cb)
      #pragma unroll
      for (int t = 0; t < 2; ++t) {
        short4v v;
        #pragma unroll
        for (int q = 0; q < 4; ++q) v[q] = f2bs(fmaxf(acc[cb][t][q], 0.f));
        *(short4v*)&yL[wv][t*16 + r][cb*16 + 4*g] = v;
      }
    __syncthreads();

    // L1 normal: rows = pos, cols = out-ch
    f32x4 acc2[4][2];
    #pragma unroll
    for (int cb = 0; cb < 4; ++cb) {
      float bv = b1[cb*16 + r];
      f32x4 bi = {bv, bv, bv, bv};
      acc2[cb][0] = bi; acc2[cb][1] = bi;
    }
    short8 af[2][2];
    #pragma unroll
    for (int t = 0; t < 2; ++t)
      #pragma unroll
      for (int s = 0; s < 2; ++s)
        af[t][s] = *(const short8*)&yL[wv][t*16 + r][s*32 + g*8];
    #pragma unroll
    for (int cb = 0; cb < 4; ++cb)
      #pragma unroll
      for (int s = 0; s < 2; ++s) {
        short8 wf = ldfrag(w1 + (cb*16 + r)*64 + s*32 + g*8);
        acc2[cb][0] = MFMA(af[0][s], wf, acc2[cb][0]);
        acc2[cb][1] = MFMA(af[1][s], wf, acc2[cb][1]);
      }
    #pragma unroll
    for (int cb = 0; cb < 4; ++cb)
      #pragma unroll
      for (int t = 0; t < 2; ++t) {
        short4v v;
        #pragma unroll
        for (int q = 0; q < 4; ++q) v[q] = f2bs(fmaxf(acc2[cb][t][q], 0.f));
        *(short4v*)(outp + (size_t)(cb*16 + r) * NT + pbase + t*16 + 4*g) = v;
      }
  }
}

// ---------------------------------------------------------------------------
// K2: per (block, channel) spatial matmul H = M1 @ M2 (n x n).
// ---------------------------------------------------------------------------
template<int N>
__global__ __launch_bounds__(256) void k2_spatial(
    const bf16* __restrict__ m1t, const bf16* __restrict__ m2t,
    bf16* __restrict__ ht, int off)
{
  constexpr int T = N / 16;
  __shared__ float A[N][N+1];
  __shared__ float B[N][N+1];
  const int b = blockIdx.x >> 6;
  const int c = blockIdx.x & 63;
  const size_t pbase = (size_t)c * NT + (size_t)off + (size_t)b * N * N;
  const int tid = threadIdx.x;

  for (int t8 = tid*8; t8 < N*N; t8 += 2048) {
    short8 v1 = *(const short8*)(m1t + pbase + t8);
    short8 v2 = *(const short8*)(m2t + pbase + t8);
    const int row = t8 / N, col = t8 - row*N;
    #pragma unroll
    for (int j = 0; j < 8; ++j) {
      A[row][col+j] = s2f(v1[j]);
      B[row][col+j] = s2f(v2[j]);
    }
  }
  __syncthreads();

  const int ti = tid >> 4, tk = tid & 15;
  float acc[T][T];
  #pragma unroll
  for (int ii = 0; ii < T; ++ii)
    #pragma unroll
    for (int kk = 0; kk < T; ++kk) acc[ii][kk] = 0.f;

  for (int j = 0; j < N; ++j) {
    float av[T], bv[T];
    #pragma unroll
    for (int ii = 0; ii < T; ++ii) av[ii] = A[ti*T+ii][j];
    #pragma unroll
    for (int kk = 0; kk < T; ++kk) bv[kk] = B[j][tk*T+kk];
    #pragma unroll
    for (int ii = 0; ii < T; ++ii)
      #pragma unroll
      for (int kk = 0; kk < T; ++kk)
        acc[ii][kk] = fmaf(av[ii], bv[kk], acc[ii][kk]);
  }

  #pragma unroll
  for (int ii = 0; ii < T; ++ii) {
    const int i = ti*T + ii;
    #pragma unroll
    for (int kk = 0; kk < T; ++kk)
      ht[pbase + i*N + tk*T + kk] = __float2bfloat16(acc[ii][kk]);
  }
}

// ---------------------------------------------------------------------------
// K3: hs2 = h + skip; u1 = relu(bn1(hs2 Wu1^T)); u2 = relu(bn2(u1 Wu2^T));
// out = u2 + hs2.
// ---------------------------------------------------------------------------
__global__ __launch_bounds__(256) void k3_update(
    const float* __restrict__ x, const bf16* __restrict__ ht,
    const float* __restrict__ Wskip, const float* __restrict__ bskip,
    const float* __restrict__ Wu1, const float* __restrict__ bu1,
    const float* __restrict__ g1, const float* __restrict__ be1,
    const float* __restrict__ rm1, const float* __restrict__ rv1,
    const float* __restrict__ Wu2, const float* __restrict__ bu2,
    const float* __restrict__ g2, const float* __restrict__ be2,
    const float* __restrict__ rm2, const float* __restrict__ rv2,
    float* __restrict__ out)
{
  __shared__ short hs2L[4][32][LS];
  __shared__ short u1L[4][32][LS];
  const int tid = threadIdx.x;
  const int wv = tid >> 6, lane = tid & 63, r = lane & 15, g = lane >> 4;
  const int pbase = blockIdx.x * 128 + wv * 32;

  short8 xf[2][2];
  #pragma unroll
  for (int t = 0; t < 2; ++t)
    #pragma unroll
    for (int s = 0; s < 2; ++s)
      xf[t][s] = ldfrag(x + (size_t)(pbase + t*16 + r) * 64 + s*32 + g*8);

  // skip (normal): rows = pos, cols = ch
  f32x4 acc[4][2];
  #pragma unroll
  for (int cb = 0; cb < 4; ++cb) {
    float bv = bskip[cb*16 + r];
    f32x4 bi = {bv, bv, bv, bv};
    acc[cb][0] = bi; acc[cb][1] = bi;
  }
  #pragma unroll
  for (int cb = 0; cb < 4; ++cb)
    #pragma unroll
    for (int s = 0; s < 2; ++s) {
      short8 wf = ldfrag(Wskip + (cb*16 + r)*64 + s*32 + g*8);
      acc[cb][0] = MFMA(xf[0][s], wf, acc[cb][0]);
      acc[cb][1] = MFMA(xf[1][s], wf, acc[cb][1]);
    }
  #pragma unroll
  for (int cb = 0; cb < 4; ++cb)
    #pragma unroll
    for (int t = 0; t < 2; ++t) {
      short4v hv = *(const short4v*)(ht + (size_t)(cb*16 + r) * NT + pbase + t*16 + 4*g);
      #pragma unroll
      for (int q = 0; q < 4; ++q) acc[cb][t][q] += s2f(hv[q]);
    }
  __syncthreads();
  #pragma unroll
  for (int cb = 0; cb < 4; ++cb)
    #pragma unroll
    for (int t = 0; t < 2; ++t)
      #pragma unroll
      for (int q = 0; q < 4; ++q)
        hs2L[wv][t*16 + 4*g + q][cb*16 + r] = f2bs(acc[cb][t][q]);
  __syncthreads();

  // u1 (transposed): rows = ch, cols = pos
  f32x4 a1[4][2];
  #pragma unroll
  for (int cb = 0; cb < 4; ++cb) {
    f32x4 bi = *(const f32x4*)(bu1 + cb*16 + 4*g);
    a1[cb][0] = bi; a1[cb][1] = bi;
  }
  short8 hf[2][2];
  #pragma unroll
  for (int t = 0; t < 2; ++t)
    #pragma unroll
    for (int s = 0; s < 2; ++s)
      hf[t][s] = *(const short8*)&hs2L[wv][t*16 + r][s*32 + g*8];
  #pragma unroll
  for (int cb = 0; cb < 4; ++cb)
    #pragma unroll
    for (int s = 0; s < 2; ++s) {
      short8 wf = ldfrag(Wu1 + (cb*16 + r)*64 + s*32 + g*8);
      a1[cb][0] = MFMA(wf, hf[0][s], a1[cb][0]);
      a1[cb][1] = MFMA(wf, hf[1][s], a1[cb][1]);
    }
  #pragma unroll
  for (int cb = 0; cb < 4; ++cb) {
    f32x4 gg = *(const f32x4*)(g1  + cb*16 + 4*g);
    f32x4 vv = *(const f32x4*)(rv1 + cb*16 + 4*g);
    f32x4 mm = *(const f32x4*)(rm1 + cb*16 + 4*g);
    f32x4 bb = *(const f32x4*)(be1 + cb*16 + 4*g);
    f32x4 sc, sh;
    #pragma unroll
    for (int q = 0; q < 4; ++q) { sc[q] = gg[q] * rsqrtf(vv[q] + 1e-5f); sh[q] = bb[q] - mm[q]*sc[q]; }
    #pragma unroll
    for (int t = 0; t < 2; ++t) {
      short4v v;
      #pragma unroll
      for (int q = 0; q < 4; ++q) v[q] = f2bs(fmaxf(a1[cb][t][q]*sc[q] + sh[q], 0.f));
      *(short4v*)&u1L[wv][t*16 + r][cb*16 + 4*g] = v;
    }
  }
  __syncthreads();

  // u2 (transposed) + residual
  f32x4 a2[4][2];
  #pragma unroll
  for (int cb = 0; cb < 4; ++cb) {
    f32x4 bi = *(const f32x4*)(bu2 + cb*16 + 4*g);
    a2[cb][0] = bi; a2[cb][1] = bi;
  }
  short8 uf[2][2];
  #pragma unroll
  for (int t = 0; t < 2; ++t)
    #pragma unroll
    for (int s = 0; s < 2; ++s)
      uf[t][s] = *(const short8*)&u1L[wv][t*16 + r][s*32 + g*8];
  #pragma unroll
  for (int cb = 0; cb < 4; ++cb)
    #pragma unroll
    for (int s = 0; s < 2; ++s) {
      short8 wf = ldfrag(Wu2 + (cb*16 + r)*64 + s*32 + g*8);
      a2[cb][0] = MFMA(wf, uf[0][s], a2[cb][0]);
      a2[cb][1] = MFMA(wf, uf[1][s], a2[cb][1]);
    }
  #pragma unroll
  for (int cb = 0; cb < 4; ++cb) {
    f32x4 gg = *(const f32x4*)(g2  + cb*16 + 4*g);
    f32x4 vv = *(const f32x4*)(rv2 + cb*16 + 4*g);
    f32x4 mm = *(const f32x4*)(rm2 + cb*16 + 4*g);
    f32x4 bb = *(const f32x4*)(be2 + cb*16 + 4*g);
    f32x4 sc, sh;
    #pragma unroll
    for (int q = 0; q < 4; ++q) { sc[q] = gg[q] * rsqrtf(vv[q] + 1e-5f); sh[q] = bb[q] - mm[q]*sc[q]; }
    #pragma unroll
    for (int t = 0; t < 2; ++t) {
      short4v hv = *(const short4v*)&hs2L[wv][t*16 + r][cb*16 + 4*g];
      f32x4 res;
      #pragma unroll
      for (int q = 0; q < 4; ++q)
        res[q] = fmaxf(a2[cb][t][q]*sc[q] + sh[q], 0.f) + s2f(hv[q]);
      *(f32x4*)(out + (size_t)(pbase + t*16 + r) * 64 + cb*16 + 4*g) = res;
    }
  }
}

// ---------------------------------------------------------------------------
extern "C" void kernel_launch(void* const* d_in, const int* in_sizes, int n_in,
                              void* d_out, int out_size, void* d_ws, size_t ws_size,
                              hipStream_t stream) {
  const float* x     = (const float*)d_in[0];
  const float* w_m1  = (const float*)d_in[1];
  const float* b_m1  = (const float*)d_in[2];
  const float* w_m2  = (const float*)d_in[3];
  const float* b_m2  = (const float*)d_in[4];
  const float* Wskip = (const float*)d_in[5];
  const float* bskip = (const float*)d_in[6];
  const float* Wu1   = (const float*)d_in[7];
  const float* bu1   = (const float*)d_in[8];
  const float* g1    = (const float*)d_in[9];
  const float* be1   = (const float*)d_in[10];
  const float* rm1   = (const float*)d_in[11];
  const float* rv1   = (const float*)d_in[12];
  const float* Wu2   = (const float*)d_in[13];
  const float* bu2   = (const float*)d_in[14];
  const float* g2    = (const float*)d_in[15];
  const float* be2   = (const float*)d_in[16];
  const float* rm2   = (const float*)d_in[17];
  const float* rv2   = (const float*)d_in[18];
  float* out = (float*)d_out;

  bf16* m1t = (bf16*)d_ws;
  bf16* m2t = m1t + (size_t)64 * NT;
  bf16* ht  = m1t;   // safe alias: k2 wg overwrites only its own read region

  k1_mlp<<<NT/128, 256, 0, stream>>>(x, w_m1, b_m1, w_m2, b_m2, m1t, m2t);

  k2_spatial<32><<<128*64, 256, 0, stream>>>(m1t, m2t, ht, 0);
  k2_spatial<48><<< 64*64, 256, 0, stream>>>(m1t, m2t, ht, 131072);
  k2_spatial<64><<< 32*64, 256, 0, stream>>>(m1t, m2t, ht, 278528);
  k2_spatial<96><<< 16*64, 256, 0, stream>>>(m1t, m2t, ht, 409600);

  k3_update<<<NT/128, 256, 0, stream>>>(x, ht, Wskip, bskip,
                                        Wu1, bu1, g1, be1, rm1, rv1,
                                        Wu2, bu2, g2, be2, rm2, rv2, out);
}

// Round 4
// 566.250 us; speedup vs baseline: 2.0518x; 1.0900x over previous
//
#include <hip/hip_runtime.h>
#include <hip/hip_bf16.h>

#define NT 557056
typedef __hip_bfloat16 bf16;
typedef __attribute__((ext_vector_type(8))) short short8;
typedef __attribute__((ext_vector_type(4))) short short4v;
typedef __attribute__((ext_vector_type(4))) float f32x4;

__device__ __forceinline__ float b2f(bf16 v){ return __bfloat162float(v); }
__device__ __forceinline__ short f2bs(float f){ bf16 h = __float2bfloat16(f); return *(short*)&h; }
__device__ __forceinline__ float s2f(short s){ bf16 h = *(bf16*)&s; return __bfloat162float(h); }

__device__ __forceinline__ short8 cvt8(float4 a, float4 b){
  short8 r;
  r[0]=f2bs(a.x); r[1]=f2bs(a.y); r[2]=f2bs(a.z); r[3]=f2bs(a.w);
  r[4]=f2bs(b.x); r[5]=f2bs(b.y); r[6]=f2bs(b.z); r[7]=f2bs(b.w);
  return r;
}
// 8 consecutive f32 -> bf16x8 MFMA fragment.
// A-role: lane holds A[row=l&15][k=(l>>4)*8+j]; B-role: B[k=(l>>4)*8+j][col=l&15].
__device__ __forceinline__ short8 ldfrag(const float* __restrict__ p){
  return cvt8(*(const float4*)p, *(const float4*)(p + 4));
}
#define MFMA(a,b,c) __builtin_amdgcn_mfma_f32_16x16x32_bf16(a, b, c, 0, 0, 0)
#define LGKM0() asm volatile("s_waitcnt lgkmcnt(0)" ::: "memory")

// ---------------------------------------------------------------------------
// K1: m1 = MLP(x; w_m1), m2 = MLP(x; w_m2). 2048 waves x 17 tiles x 16 pos.
// Weights register-resident (32 frags). Wave-private LDS transpose, NO barriers.
// ---------------------------------------------------------------------------
__global__ __launch_bounds__(256, 2) void k1_mlp(
    const float* __restrict__ x,
    const float* __restrict__ w_m1, const float* __restrict__ b_m1,
    const float* __restrict__ w_m2, const float* __restrict__ b_m2,
    bf16* __restrict__ m1t, bf16* __restrict__ m2t)
{
  __shared__ short yL[4][16][72];   // per-wave [16 pos][64 ch + pad], 144B rows
  const int tid = threadIdx.x;
  const int wv = tid >> 6, lane = tid & 63, r = lane & 15, g = lane >> 4;
  const int wid = blockIdx.x * 4 + wv;   // 0..2047

  // ---- hoist weights into registers (once per wave) ----
  short8 wf[4][4][2];   // [layer: m1L0,m1L1,m2L0,m2L1][cb][s]
  {
    const float* wp0 = w_m1;         const float* wp1 = w_m1 + 4096;
    const float* wp2 = w_m2;         const float* wp3 = w_m2 + 4096;
    #pragma unroll
    for (int cb = 0; cb < 4; ++cb)
      #pragma unroll
      for (int s = 0; s < 2; ++s) {
        const int o = (cb*16 + r)*64 + s*32 + g*8;
        wf[0][cb][s] = ldfrag(wp0 + o);
        wf[1][cb][s] = ldfrag(wp1 + o);
        wf[2][cb][s] = ldfrag(wp2 + o);
        wf[3][cb][s] = ldfrag(wp3 + o);
      }
  }
  f32x4 b0v[2][4];  // L0 bias, col-wise (out-ch = cb*16+4g+q)
  float b1v[2][4];  // L1 bias, row-wise (out-ch = cb*16+r)
  #pragma unroll
  for (int m = 0; m < 2; ++m) {
    const float* bb = m ? b_m2 : b_m1;
    #pragma unroll
    for (int cb = 0; cb < 4; ++cb) {
      b0v[m][cb] = *(const f32x4*)(bb + cb*16 + 4*g);
      b1v[m][cb] = bb[64 + cb*16 + r];
    }
  }

  size_t pb = (size_t)wid * (17*16);
  const float* xp0 = x + (pb + r)*64 + g*8;
  float4 xr0 = *(const float4*)(xp0);
  float4 xr1 = *(const float4*)(xp0 + 4);
  float4 xr2 = *(const float4*)(xp0 + 32);
  float4 xr3 = *(const float4*)(xp0 + 36);

  for (int t = 0; t < 17; ++t, pb += 16) {
    short8 xf0 = cvt8(xr0, xr1);
    short8 xf1 = cvt8(xr2, xr3);
    if (t < 16) {   // prefetch next tile under this tile's MFMAs
      const float* xn = x + (pb + 16 + r)*64 + g*8;
      xr0 = *(const float4*)(xn);
      xr1 = *(const float4*)(xn + 4);
      xr2 = *(const float4*)(xn + 32);
      xr3 = *(const float4*)(xn + 36);
    }
    #pragma unroll
    for (int m = 0; m < 2; ++m) {
      // L0 transposed: C[row=out-ch][col=pos]
      f32x4 acc[4];
      #pragma unroll
      for (int cb = 0; cb < 4; ++cb) acc[cb] = b0v[m][cb];
      #pragma unroll
      for (int cb = 0; cb < 4; ++cb) {
        acc[cb] = MFMA(wf[2*m][cb][0], xf0, acc[cb]);
        acc[cb] = MFMA(wf[2*m][cb][1], xf1, acc[cb]);
      }
      #pragma unroll
      for (int cb = 0; cb < 4; ++cb) {
        short4v v;
        #pragma unroll
        for (int q = 0; q < 4; ++q) v[q] = f2bs(fmaxf(acc[cb][q], 0.f));
        *(short4v*)&yL[wv][r][cb*16 + 4*g] = v;   // [pos=r][ch]
      }
      LGKM0();
      short8 a0 = *(const short8*)&yL[wv][r][g*8];
      short8 a1 = *(const short8*)&yL[wv][r][32 + g*8];
      // L1 normal: C[row=pos][col=out-ch]
      f32x4 acc2[4];
      #pragma unroll
      for (int cb = 0; cb < 4; ++cb) {
        const float bv = b1v[m][cb];
        acc2[cb] = (f32x4){bv, bv, bv, bv};
      }
      #pragma unroll
      for (int cb = 0; cb < 4; ++cb) {
        acc2[cb] = MFMA(a0, wf[2*m+1][cb][0], acc2[cb]);
        acc2[cb] = MFMA(a1, wf[2*m+1][cb][1], acc2[cb]);
      }
      bf16* op = m ? m2t : m1t;
      #pragma unroll
      for (int cb = 0; cb < 4; ++cb) {
        short4v v;
        #pragma unroll
        for (int q = 0; q < 4; ++q) v[q] = f2bs(fmaxf(acc2[cb][q], 0.f));
        *(short4v*)(op + (size_t)(cb*16 + r) * NT + pb + 4*g) = v;  // ch-major
      }
    }
  }
}

// ---------------------------------------------------------------------------
// K2: per (block, channel) spatial matmul H = M1 @ M2 (n x n).
// A staged transposed, B row-major, f32 LDS padded to SA=N+4 (conflict-free,
// aligned vector reads). ht aliases m1t (plane fully read before write).
// ---------------------------------------------------------------------------
template<int N>
__global__ __launch_bounds__(256) void k2_spatial(
    const bf16* __restrict__ m1t, const bf16* __restrict__ m2t,
    bf16* __restrict__ ht, int off)
{
  constexpr int T = N / 16;
  constexpr int SA = N + 4;
  __shared__ __align__(16) float AT[N*SA];  // AT[k][j] = A[j][k]
  __shared__ __align__(16) float Bs[N*SA];  // Bs[j][k] = B[j][k]
  const int b = blockIdx.x >> 6;
  const int c = blockIdx.x & 63;
  const size_t pbase = (size_t)c * NT + (size_t)off + (size_t)b * N * N;
  const int tid = threadIdx.x;

  for (int idx = tid*4; idx < N*N; idx += 1024) {
    short4v a4 = *(const short4v*)(m1t + pbase + idx);
    short4v b4 = *(const short4v*)(m2t + pbase + idx);
    const int j = idx / N, k0 = idx - j*N;
    f32x4 bf;
    #pragma unroll
    for (int q = 0; q < 4; ++q) bf[q] = s2f(b4[q]);
    *(f32x4*)&Bs[j*SA + k0] = bf;
    #pragma unroll
    for (int q = 0; q < 4; ++q) AT[(k0+q)*SA + j] = s2f(a4[q]);
  }
  __syncthreads();

  const int ti = tid >> 4, tk = tid & 15;
  float acc[T][T];
  #pragma unroll
  for (int ii = 0; ii < T; ++ii)
    #pragma unroll
    for (int kk = 0; kk < T; ++kk) acc[ii][kk] = 0.f;

  for (int j = 0; j < N; ++j) {
    const float* ar = &AT[j*SA + ti*T];
    const float* br = &Bs[j*SA + tk*T];
    float av[T], bv[T];
    if constexpr (T == 2) {
      float2 a2 = *(const float2*)ar; av[0]=a2.x; av[1]=a2.y;
      float2 b2 = *(const float2*)br; bv[0]=b2.x; bv[1]=b2.y;
    } else if constexpr (T == 3) {
      av[0]=ar[0]; av[1]=ar[1]; av[2]=ar[2];
      bv[0]=br[0]; bv[1]=br[1]; bv[2]=br[2];
    } else if constexpr (T == 4) {
      float4 a4 = *(const float4*)ar; av[0]=a4.x; av[1]=a4.y; av[2]=a4.z; av[3]=a4.w;
      float4 b4 = *(const float4*)br; bv[0]=b4.x; bv[1]=b4.y; bv[2]=b4.z; bv[3]=b4.w;
    } else {  // T == 6
      #pragma unroll
      for (int p = 0; p < 3; ++p) {
        float2 a2 = *(const float2*)(ar + 2*p); av[2*p]=a2.x; av[2*p+1]=a2.y;
        float2 b2 = *(const float2*)(br + 2*p); bv[2*p]=b2.x; bv[2*p+1]=b2.y;
      }
    }
    #pragma unroll
    for (int ii = 0; ii < T; ++ii)
      #pragma unroll
      for (int kk = 0; kk < T; ++kk)
        acc[ii][kk] = fmaf(av[ii], bv[kk], acc[ii][kk]);
  }

  #pragma unroll
  for (int ii = 0; ii < T; ++ii) {
    const int row = ti*T + ii;
    bf16* dst = ht + pbase + row*N + tk*T;
    unsigned short tmp[T];
    #pragma unroll
    for (int kk = 0; kk < T; ++kk) tmp[kk] = (unsigned short)f2bs(acc[ii][kk]);
    if constexpr (T == 2) {
      *(unsigned int*)dst = (unsigned int)tmp[0] | ((unsigned int)tmp[1] << 16);
    } else if constexpr (T == 3) {
      ((unsigned short*)dst)[0] = tmp[0];
      ((unsigned short*)dst)[1] = tmp[1];
      ((unsigned short*)dst)[2] = tmp[2];
    } else if constexpr (T == 4) {
      short4v v; v[0]=(short)tmp[0]; v[1]=(short)tmp[1]; v[2]=(short)tmp[2]; v[3]=(short)tmp[3];
      *(short4v*)dst = v;
    } else {  // T == 6, 4B-aligned
      #pragma unroll
      for (int p = 0; p < 3; ++p)
        *((unsigned int*)dst + p) = (unsigned int)tmp[2*p] | ((unsigned int)tmp[2*p+1] << 16);
    }
  }
}

// ---------------------------------------------------------------------------
// K3: hs2 = h + x@Wskip^T + b; u1 = relu(bn1(hs2@Wu1^T)); u2 = relu(bn2(u1@Wu2^T));
// out = u2 + hs2. Same wave/tile structure as k1; BN consts folded & reg-resident.
// ---------------------------------------------------------------------------
__global__ __launch_bounds__(256, 2) void k3_update(
    const float* __restrict__ x, const bf16* __restrict__ ht,
    const float* __restrict__ Wskip, const float* __restrict__ bskip,
    const float* __restrict__ Wu1, const float* __restrict__ bu1,
    const float* __restrict__ g1, const float* __restrict__ be1,
    const float* __restrict__ rm1, const float* __restrict__ rv1,
    const float* __restrict__ Wu2, const float* __restrict__ bu2,
    const float* __restrict__ g2, const float* __restrict__ be2,
    const float* __restrict__ rm2, const float* __restrict__ rv2,
    float* __restrict__ out)
{
  __shared__ short hs2L[4][16][88];  // scalar-written: stride 176B, ~2-way
  __shared__ short u1L[4][16][72];   // vector-written: stride 144B
  const int tid = threadIdx.x;
  const int wv = tid >> 6, lane = tid & 63, r = lane & 15, g = lane >> 4;
  const int wid = blockIdx.x * 4 + wv;

  short8 wsk[4][2], w1f[4][2], w2f[4][2];
  #pragma unroll
  for (int cb = 0; cb < 4; ++cb)
    #pragma unroll
    for (int s = 0; s < 2; ++s) {
      const int o = (cb*16 + r)*64 + s*32 + g*8;
      wsk[cb][s] = ldfrag(Wskip + o);
      w1f[cb][s] = ldfrag(Wu1 + o);
      w2f[cb][s] = ldfrag(Wu2 + o);
    }
  float bskv[4];
  f32x4 sc1v[4], sh1v[4], sc2v[4], sh2v[4];
  #pragma unroll
  for (int cb = 0; cb < 4; ++cb) {
    bskv[cb] = bskip[cb*16 + r];
    const int o = cb*16 + 4*g;
    f32x4 gg1 = *(const f32x4*)(g1 + o),  vv1 = *(const f32x4*)(rv1 + o);
    f32x4 mm1 = *(const f32x4*)(rm1 + o), bb1 = *(const f32x4*)(be1 + o);
    f32x4 bu1v = *(const f32x4*)(bu1 + o);
    f32x4 gg2 = *(const f32x4*)(g2 + o),  vv2 = *(const f32x4*)(rv2 + o);
    f32x4 mm2 = *(const f32x4*)(rm2 + o), bb2 = *(const f32x4*)(be2 + o);
    f32x4 bu2v = *(const f32x4*)(bu2 + o);
    #pragma unroll
    for (int q = 0; q < 4; ++q) {
      const float s1 = gg1[q] * rsqrtf(vv1[q] + 1e-5f);
      sc1v[cb][q] = s1; sh1v[cb][q] = bb1[q] + (bu1v[q] - mm1[q]) * s1;
      const float s2 = gg2[q] * rsqrtf(vv2[q] + 1e-5f);
      sc2v[cb][q] = s2; sh2v[cb][q] = bb2[q] + (bu2v[q] - mm2[q]) * s2;
    }
  }

  size_t pb = (size_t)wid * (17*16);
  const float* xp0 = x + (pb + r)*64 + g*8;
  float4 xr0 = *(const float4*)(xp0);
  float4 xr1 = *(const float4*)(xp0 + 4);
  float4 xr2 = *(const float4*)(xp0 + 32);
  float4 xr3 = *(const float4*)(xp0 + 36);

  for (int t = 0; t < 17; ++t, pb += 16) {
    short8 xf0 = cvt8(xr0, xr1);
    short8 xf1 = cvt8(xr2, xr3);
    if (t < 16) {
      const float* xn = x + (pb + 16 + r)*64 + g*8;
      xr0 = *(const float4*)(xn);
      xr1 = *(const float4*)(xn + 4);
      xr2 = *(const float4*)(xn + 32);
      xr3 = *(const float4*)(xn + 36);
    }
    // h tile loads (ch-major), overlapped with skip MFMAs below
    short4v hv[4];
    #pragma unroll
    for (int cb = 0; cb < 4; ++cb)
      hv[cb] = *(const short4v*)(ht + (size_t)(cb*16 + r) * NT + pb + 4*g);

    // skip GEMM (normal): C[row=pos(4g+q)][col=ch(cb*16+r)]
    f32x4 acc[4];
    #pragma unroll
    for (int cb = 0; cb < 4; ++cb) acc[cb] = (f32x4){bskv[cb], bskv[cb], bskv[cb], bskv[cb]};
    #pragma unroll
    for (int cb = 0; cb < 4; ++cb) {
      acc[cb] = MFMA(xf0, wsk[cb][0], acc[cb]);
      acc[cb] = MFMA(xf1, wsk[cb][1], acc[cb]);
    }
    #pragma unroll
    for (int cb = 0; cb < 4; ++cb)
      #pragma unroll
      for (int q = 0; q < 4; ++q) acc[cb][q] += s2f(hv[cb][q]);
    // hs2 -> LDS [pos][ch] (scalar transpose-writes)
    #pragma unroll
    for (int cb = 0; cb < 4; ++cb)
      #pragma unroll
      for (int q = 0; q < 4; ++q)
        hs2L[wv][4*g + q][cb*16 + r] = f2bs(acc[cb][q]);
    LGKM0();
    short8 h0 = *(const short8*)&hs2L[wv][r][g*8];
    short8 h1 = *(const short8*)&hs2L[wv][r][32 + g*8];

    // u1 (transposed): C[row=ch][col=pos]
    f32x4 a1[4];
    #pragma unroll
    for (int cb = 0; cb < 4; ++cb) a1[cb] = (f32x4){0.f, 0.f, 0.f, 0.f};
    #pragma unroll
    for (int cb = 0; cb < 4; ++cb) {
      a1[cb] = MFMA(w1f[cb][0], h0, a1[cb]);
      a1[cb] = MFMA(w1f[cb][1], h1, a1[cb]);
    }
    #pragma unroll
    for (int cb = 0; cb < 4; ++cb) {
      short4v v;
      #pragma unroll
      for (int q = 0; q < 4; ++q)
        v[q] = f2bs(fmaxf(a1[cb][q]*sc1v[cb][q] + sh1v[cb][q], 0.f));
      *(short4v*)&u1L[wv][r][cb*16 + 4*g] = v;  // [pos=r][ch]
    }
    LGKM0();
    short8 u0 = *(const short8*)&u1L[wv][r][g*8];
    short8 u1f = *(const short8*)&u1L[wv][r][32 + g*8];

    // u2 (transposed) + residual
    f32x4 a2[4];
    #pragma unroll
    for (int cb = 0; cb < 4; ++cb) a2[cb] = (f32x4){0.f, 0.f, 0.f, 0.f};
    #pragma unroll
    for (int cb = 0; cb < 4; ++cb) {
      a2[cb] = MFMA(w2f[cb][0], u0, a2[cb]);
      a2[cb] = MFMA(w2f[cb][1], u1f, a2[cb]);
    }
    #pragma unroll
    for (int cb = 0; cb < 4; ++cb) {
      short4v hres = *(const short4v*)&hs2L[wv][r][cb*16 + 4*g];
      f32x4 res;
      #pragma unroll
      for (int q = 0; q < 4; ++q)
        res[q] = fmaxf(a2[cb][q]*sc2v[cb][q] + sh2v[cb][q], 0.f) + s2f(hres[q]);
      *(f32x4*)(out + (pb + r)*64 + cb*16 + 4*g) = res;
    }
  }
}

// ---------------------------------------------------------------------------
extern "C" void kernel_launch(void* const* d_in, const int* in_sizes, int n_in,
                              void* d_out, int out_size, void* d_ws, size_t ws_size,
                              hipStream_t stream) {
  const float* x     = (const float*)d_in[0];
  const float* w_m1  = (const float*)d_in[1];
  const float* b_m1  = (const float*)d_in[2];
  const float* w_m2  = (const float*)d_in[3];
  const float* b_m2  = (const float*)d_in[4];
  const float* Wskip = (const float*)d_in[5];
  const float* bskip = (const float*)d_in[6];
  const float* Wu1   = (const float*)d_in[7];
  const float* bu1   = (const float*)d_in[8];
  const float* g1    = (const float*)d_in[9];
  const float* be1   = (const float*)d_in[10];
  const float* rm1   = (const float*)d_in[11];
  const float* rv1   = (const float*)d_in[12];
  const float* Wu2   = (const float*)d_in[13];
  const float* bu2   = (const float*)d_in[14];
  const float* g2    = (const float*)d_in[15];
  const float* be2   = (const float*)d_in[16];
  const float* rm2   = (const float*)d_in[17];
  const float* rv2   = (const float*)d_in[18];
  float* out = (float*)d_out;

  bf16* m1t = (bf16*)d_ws;
  bf16* m2t = m1t + (size_t)64 * NT;
  bf16* ht  = m1t;   // safe alias: each k2 block overwrites only its own region

  k1_mlp<<<512, 256, 0, stream>>>(x, w_m1, b_m1, w_m2, b_m2, m1t, m2t);

  k2_spatial<32><<<128*64, 256, 0, stream>>>(m1t, m2t, ht, 0);
  k2_spatial<48><<< 64*64, 256, 0, stream>>>(m1t, m2t, ht, 131072);
  k2_spatial<64><<< 32*64, 256, 0, stream>>>(m1t, m2t, ht, 278528);
  k2_spatial<96><<< 16*64, 256, 0, stream>>>(m1t, m2t, ht, 409600);

  k3_update<<<512, 256, 0, stream>>>(x, ht, Wskip, bskip,
                                     Wu1, bu1, g1, be1, rm1, rv1,
                                     Wu2, bu2, g2, be2, rm2, rv2, out);
}

// Round 5
// 557.449 us; speedup vs baseline: 2.0842x; 1.0158x over previous
//
#include <hip/hip_runtime.h>
#include <hip/hip_bf16.h>

#define NT 557056
typedef __hip_bfloat16 bf16;
typedef __attribute__((ext_vector_type(8))) short short8;
typedef __attribute__((ext_vector_type(4))) short short4v;
typedef __attribute__((ext_vector_type(4))) float f32x4;

__device__ __forceinline__ short f2bs(float f){ bf16 h = __float2bfloat16(f); return *(short*)&h; }
__device__ __forceinline__ float s2f(short s){ bf16 h = *(bf16*)&s; return __bfloat162float(h); }

__device__ __forceinline__ short8 cvt8(float4 a, float4 b){
  short8 r;
  r[0]=f2bs(a.x); r[1]=f2bs(a.y); r[2]=f2bs(a.z); r[3]=f2bs(a.w);
  r[4]=f2bs(b.x); r[5]=f2bs(b.y); r[6]=f2bs(b.z); r[7]=f2bs(b.w);
  return r;
}
// 8 consecutive f32 -> bf16x8 MFMA fragment.
// A-role: lane holds A[row=l&15][k=(l>>4)*8+j]; B-role: B[k=(l>>4)*8+j][col=l&15].
__device__ __forceinline__ short8 ldfrag(const float* __restrict__ p){
  return cvt8(*(const float4*)p, *(const float4*)(p + 4));
}
__device__ __forceinline__ short8 ldfrag_s(const float* __restrict__ p, float s){
  float4 a = *(const float4*)p, b = *(const float4*)(p + 4);
  a.x*=s; a.y*=s; a.z*=s; a.w*=s; b.x*=s; b.y*=s; b.z*=s; b.w*=s;
  return cvt8(a, b);
}
#define MFMA(a,b,c) __builtin_amdgcn_mfma_f32_16x16x32_bf16(a, b, c, 0, 0, 0)

#define LS 88   // LDS row stride in shorts (176B rows)

// ---------------------------------------------------------------------------
// K1: m1 = MLP(x; w_m1), m2 = MLP(x; w_m2). 4352 waves x 4 tiles x 32 pos.
// Weights register/AGPR-resident. Wave-private LDS transpose, no barriers,
// no asm waits (compiler emits precise lgkmcnt). 32-pos tiles -> every
// channel-major store covers 64B per channel row (no HBM write amplification).
// ---------------------------------------------------------------------------
__global__ __launch_bounds__(256, 2) void k1_mlp(
    const float* __restrict__ x,
    const float* __restrict__ w_m1, const float* __restrict__ b_m1,
    const float* __restrict__ w_m2, const float* __restrict__ b_m2,
    bf16* __restrict__ m1t, bf16* __restrict__ m2t)
{
  __shared__ short yL[4][2][32][LS];   // [wave][mlp][pos][ch+pad]
  const int tid = threadIdx.x;
  const int wv = tid >> 6, lane = tid & 63, r = lane & 15, g = lane >> 4;
  const int wid = blockIdx.x * 4 + wv;   // 0..4351

  // ---- hoist weights (once per wave) ----
  short8 wf[4][4][2];   // [m1L0,m1L1,m2L0,m2L1][cb][s]
  #pragma unroll
  for (int cb = 0; cb < 4; ++cb)
    #pragma unroll
    for (int s = 0; s < 2; ++s) {
      const int o = (cb*16 + r)*64 + s*32 + g*8;
      wf[0][cb][s] = ldfrag(w_m1 + o);
      wf[1][cb][s] = ldfrag(w_m1 + 4096 + o);
      wf[2][cb][s] = ldfrag(w_m2 + o);
      wf[3][cb][s] = ldfrag(w_m2 + 4096 + o);
    }
  f32x4 b0v[2][4];  // L0 bias (transposed C: rows=ch=4g+q)
  float b1v[2][4];  // L1 bias (normal C: col=ch=r)
  #pragma unroll
  for (int m = 0; m < 2; ++m) {
    const float* bb = m ? b_m2 : b_m1;
    #pragma unroll
    for (int cb = 0; cb < 4; ++cb) {
      b0v[m][cb] = *(const f32x4*)(bb + cb*16 + 4*g);
      b1v[m][cb] = bb[64 + cb*16 + r];
    }
  }

  size_t pb = (size_t)wid * 128;

  float4 xr[8];
  #pragma unroll
  for (int h = 0; h < 2; ++h) {
    const float* xp = x + (pb + h*16 + r)*64 + g*8;
    xr[4*h+0] = *(const float4*)(xp);
    xr[4*h+1] = *(const float4*)(xp + 4);
    xr[4*h+2] = *(const float4*)(xp + 32);
    xr[4*h+3] = *(const float4*)(xp + 36);
  }

  for (int t = 0; t < 4; ++t, pb += 32) {
    short8 xf[2][2];
    xf[0][0] = cvt8(xr[0], xr[1]);  xf[0][1] = cvt8(xr[2], xr[3]);
    xf[1][0] = cvt8(xr[4], xr[5]);  xf[1][1] = cvt8(xr[6], xr[7]);
    if (t < 3) {   // prefetch next tile under this tile's compute
      #pragma unroll
      for (int h = 0; h < 2; ++h) {
        const float* xp = x + (pb + 32 + h*16 + r)*64 + g*8;
        xr[4*h+0] = *(const float4*)(xp);
        xr[4*h+1] = *(const float4*)(xp + 4);
        xr[4*h+2] = *(const float4*)(xp + 32);
        xr[4*h+3] = *(const float4*)(xp + 36);
      }
    }
    #pragma unroll
    for (int m = 0; m < 2; ++m) {
      // L0 transposed: C[row=ch][col=pos]; lane -> pos=th*16+r? no: col=r(pos), rows=4g+q(ch)
      f32x4 acc[4][2];
      #pragma unroll
      for (int cb = 0; cb < 4; ++cb) { acc[cb][0] = b0v[m][cb]; acc[cb][1] = b0v[m][cb]; }
      #pragma unroll
      for (int cb = 0; cb < 4; ++cb)
        #pragma unroll
        for (int s = 0; s < 2; ++s) {
          acc[cb][0] = MFMA(wf[2*m][cb][s], xf[0][s], acc[cb][0]);
          acc[cb][1] = MFMA(wf[2*m][cb][s], xf[1][s], acc[cb][1]);
        }
      #pragma unroll
      for (int cb = 0; cb < 4; ++cb)
        #pragma unroll
        for (int th = 0; th < 2; ++th) {
          short4v v;
          #pragma unroll
          for (int q = 0; q < 4; ++q) v[q] = f2bs(fmaxf(acc[cb][th][q], 0.f));
          *(short4v*)&yL[wv][m][th*16 + r][cb*16 + 4*g] = v;   // [pos][ch-run]
        }
      short8 af[2][2];
      #pragma unroll
      for (int th = 0; th < 2; ++th)
        #pragma unroll
        for (int s = 0; s < 2; ++s)
          af[th][s] = *(const short8*)&yL[wv][m][th*16 + r][s*32 + g*8];
      // L1 normal: C[row=pos(4g+q)][col=ch(r)]
      f32x4 acc2[4][2];
      #pragma unroll
      for (int cb = 0; cb < 4; ++cb) {
        const float bv = b1v[m][cb];
        acc2[cb][0] = (f32x4){bv,bv,bv,bv};
        acc2[cb][1] = (f32x4){bv,bv,bv,bv};
      }
      #pragma unroll
      for (int cb = 0; cb < 4; ++cb)
        #pragma unroll
        for (int s = 0; s < 2; ++s) {
          acc2[cb][0] = MFMA(af[0][s], wf[2*m+1][cb][s], acc2[cb][0]);
          acc2[cb][1] = MFMA(af[1][s], wf[2*m+1][cb][s], acc2[cb][1]);
        }
      bf16* op = m ? m2t : m1t;
      #pragma unroll
      for (int cb = 0; cb < 4; ++cb)
        #pragma unroll
        for (int th = 0; th < 2; ++th) {
          short4v v;
          #pragma unroll
          for (int q = 0; q < 4; ++q) v[q] = f2bs(fmaxf(acc2[cb][th][q], 0.f));
          // ch-major: channel cb*16+r, positions pb+th*16+4g..+3 (64B/ch per tile)
          *(short4v*)(op + (size_t)(cb*16 + r) * NT + pb + th*16 + 4*g) = v;
        }
    }
  }
}

// ---------------------------------------------------------------------------
// K2: per (block, channel) spatial matmul H = M1 @ M2 (n x n). Unchanged.
// ---------------------------------------------------------------------------
template<int N>
__global__ __launch_bounds__(256) void k2_spatial(
    const bf16* __restrict__ m1t, const bf16* __restrict__ m2t,
    bf16* __restrict__ ht, int off)
{
  constexpr int T = N / 16;
  constexpr int SA = N + 4;
  __shared__ __align__(16) float AT[N*SA];  // AT[k][j] = A[j][k]
  __shared__ __align__(16) float Bs[N*SA];  // Bs[j][k] = B[j][k]
  const int b = blockIdx.x >> 6;
  const int c = blockIdx.x & 63;
  const size_t pbase = (size_t)c * NT + (size_t)off + (size_t)b * N * N;
  const int tid = threadIdx.x;

  for (int idx = tid*4; idx < N*N; idx += 1024) {
    short4v a4 = *(const short4v*)(m1t + pbase + idx);
    short4v b4 = *(const short4v*)(m2t + pbase + idx);
    const int j = idx / N, k0 = idx - j*N;
    f32x4 bf;
    #pragma unroll
    for (int q = 0; q < 4; ++q) bf[q] = s2f(b4[q]);
    *(f32x4*)&Bs[j*SA + k0] = bf;
    #pragma unroll
    for (int q = 0; q < 4; ++q) AT[(k0+q)*SA + j] = s2f(a4[q]);
  }
  __syncthreads();

  const int ti = tid >> 4, tk = tid & 15;
  float acc[T][T];
  #pragma unroll
  for (int ii = 0; ii < T; ++ii)
    #pragma unroll
    for (int kk = 0; kk < T; ++kk) acc[ii][kk] = 0.f;

  for (int j = 0; j < N; ++j) {
    const float* ar = &AT[j*SA + ti*T];
    const float* br = &Bs[j*SA + tk*T];
    float av[T], bv[T];
    if constexpr (T == 2) {
      float2 a2 = *(const float2*)ar; av[0]=a2.x; av[1]=a2.y;
      float2 b2 = *(const float2*)br; bv[0]=b2.x; bv[1]=b2.y;
    } else if constexpr (T == 3) {
      av[0]=ar[0]; av[1]=ar[1]; av[2]=ar[2];
      bv[0]=br[0]; bv[1]=br[1]; bv[2]=br[2];
    } else if constexpr (T == 4) {
      float4 a4 = *(const float4*)ar; av[0]=a4.x; av[1]=a4.y; av[2]=a4.z; av[3]=a4.w;
      float4 b4 = *(const float4*)br; bv[0]=b4.x; bv[1]=b4.y; bv[2]=b4.z; bv[3]=b4.w;
    } else {  // T == 6
      #pragma unroll
      for (int p = 0; p < 3; ++p) {
        float2 a2 = *(const float2*)(ar + 2*p); av[2*p]=a2.x; av[2*p+1]=a2.y;
        float2 b2 = *(const float2*)(br + 2*p); bv[2*p]=b2.x; bv[2*p+1]=b2.y;
      }
    }
    #pragma unroll
    for (int ii = 0; ii < T; ++ii)
      #pragma unroll
      for (int kk = 0; kk < T; ++kk)
        acc[ii][kk] = fmaf(av[ii], bv[kk], acc[ii][kk]);
  }

  #pragma unroll
  for (int ii = 0; ii < T; ++ii) {
    const int row = ti*T + ii;
    bf16* dst = ht + pbase + row*N + tk*T;
    unsigned short tmp[T];
    #pragma unroll
    for (int kk = 0; kk < T; ++kk) tmp[kk] = (unsigned short)f2bs(acc[ii][kk]);
    if constexpr (T == 2) {
      *(unsigned int*)dst = (unsigned int)tmp[0] | ((unsigned int)tmp[1] << 16);
    } else if constexpr (T == 3) {
      ((unsigned short*)dst)[0] = tmp[0];
      ((unsigned short*)dst)[1] = tmp[1];
      ((unsigned short*)dst)[2] = tmp[2];
    } else if constexpr (T == 4) {
      short4v v; v[0]=(short)tmp[0]; v[1]=(short)tmp[1]; v[2]=(short)tmp[2]; v[3]=(short)tmp[3];
      *(short4v*)dst = v;
    } else {  // T == 6, 4B-aligned
      #pragma unroll
      for (int p = 0; p < 3; ++p)
        *((unsigned int*)dst + p) = (unsigned int)tmp[2*p] | ((unsigned int)tmp[2*p+1] << 16);
    }
  }
}

// ---------------------------------------------------------------------------
// K3: hs2 = h + x@Wskip^T + b; u1 = relu(bn1(hs2@Wu1^T+bu1));
// u2 = relu(bn2(u1@Wu2^T+bu2)); out = u2 + hs2.
// 4352 waves x 4 tiles x 32 pos; BN folded into weight frags + bias vectors.
// ---------------------------------------------------------------------------
__global__ __launch_bounds__(256, 2) void k3_update(
    const float* __restrict__ x, const bf16* __restrict__ ht,
    const float* __restrict__ Wskip, const float* __restrict__ bskip,
    const float* __restrict__ Wu1, const float* __restrict__ bu1,
    const float* __restrict__ g1, const float* __restrict__ be1,
    const float* __restrict__ rm1, const float* __restrict__ rv1,
    const float* __restrict__ Wu2, const float* __restrict__ bu2,
    const float* __restrict__ g2, const float* __restrict__ be2,
    const float* __restrict__ rm2, const float* __restrict__ rv2,
    float* __restrict__ out)
{
  __shared__ short hs2L[4][32][LS];
  __shared__ short u1L[4][32][LS];
  const int tid = threadIdx.x;
  const int wv = tid >> 6, lane = tid & 63, r = lane & 15, g = lane >> 4;
  const int wid = blockIdx.x * 4 + wv;

  // ---- weights with BN folded: W1' = sc1 o Wu1, b1' = be1 + (bu1-rm1)*sc1 ----
  short8 wsk[4][2], w1f[4][2], w2f[4][2];
  float bskv[4];
  f32x4 b1c[4], b2c[4];
  #pragma unroll
  for (int cb = 0; cb < 4; ++cb) {
    const int row = cb*16 + r;
    const float s1 = g1[row] * rsqrtf(rv1[row] + 1e-5f);
    const float s2 = g2[row] * rsqrtf(rv2[row] + 1e-5f);
    #pragma unroll
    for (int s = 0; s < 2; ++s) {
      const int o = row*64 + s*32 + g*8;
      wsk[cb][s] = ldfrag(Wskip + o);
      w1f[cb][s] = ldfrag_s(Wu1 + o, s1);
      w2f[cb][s] = ldfrag_s(Wu2 + o, s2);
    }
    bskv[cb] = bskip[row];
    const int o4 = cb*16 + 4*g;
    f32x4 gg1 = *(const f32x4*)(g1 + o4),  vv1 = *(const f32x4*)(rv1 + o4);
    f32x4 mm1 = *(const f32x4*)(rm1 + o4), bb1 = *(const f32x4*)(be1 + o4);
    f32x4 u1b = *(const f32x4*)(bu1 + o4);
    f32x4 gg2 = *(const f32x4*)(g2 + o4),  vv2 = *(const f32x4*)(rv2 + o4);
    f32x4 mm2 = *(const f32x4*)(rm2 + o4), bb2 = *(const f32x4*)(be2 + o4);
    f32x4 u2b = *(const f32x4*)(bu2 + o4);
    #pragma unroll
    for (int q = 0; q < 4; ++q) {
      const float c1 = gg1[q] * rsqrtf(vv1[q] + 1e-5f);
      b1c[cb][q] = bb1[q] + (u1b[q] - mm1[q]) * c1;
      const float c2 = gg2[q] * rsqrtf(vv2[q] + 1e-5f);
      b2c[cb][q] = bb2[q] + (u2b[q] - mm2[q]) * c2;
    }
  }

  size_t pb = (size_t)wid * 128;

  float4 xr[8];
  #pragma unroll
  for (int h = 0; h < 2; ++h) {
    const float* xp = x + (pb + h*16 + r)*64 + g*8;
    xr[4*h+0] = *(const float4*)(xp);
    xr[4*h+1] = *(const float4*)(xp + 4);
    xr[4*h+2] = *(const float4*)(xp + 32);
    xr[4*h+3] = *(const float4*)(xp + 36);
  }

  for (int t = 0; t < 4; ++t, pb += 32) {
    short8 xf[2][2];
    xf[0][0] = cvt8(xr[0], xr[1]);  xf[0][1] = cvt8(xr[2], xr[3]);
    xf[1][0] = cvt8(xr[4], xr[5]);  xf[1][1] = cvt8(xr[6], xr[7]);
    if (t < 3) {
      #pragma unroll
      for (int h = 0; h < 2; ++h) {
        const float* xp = x + (pb + 32 + h*16 + r)*64 + g*8;
        xr[4*h+0] = *(const float4*)(xp);
        xr[4*h+1] = *(const float4*)(xp + 4);
        xr[4*h+2] = *(const float4*)(xp + 32);
        xr[4*h+3] = *(const float4*)(xp + 36);
      }
    }
    // h tile loads (ch-major, 64B/ch across th)
    short4v hv[4][2];
    #pragma unroll
    for (int cb = 0; cb < 4; ++cb)
      #pragma unroll
      for (int th = 0; th < 2; ++th)
        hv[cb][th] = *(const short4v*)(ht + (size_t)(cb*16 + r) * NT + pb + th*16 + 4*g);

    // skip GEMM (normal): C[row=pos(4g+q)][col=ch(r)]
    f32x4 acc[4][2];
    #pragma unroll
    for (int cb = 0; cb < 4; ++cb) {
      acc[cb][0] = (f32x4){bskv[cb], bskv[cb], bskv[cb], bskv[cb]};
      acc[cb][1] = acc[cb][0];
    }
    #pragma unroll
    for (int cb = 0; cb < 4; ++cb)
      #pragma unroll
      for (int s = 0; s < 2; ++s) {
        acc[cb][0] = MFMA(xf[0][s], wsk[cb][s], acc[cb][0]);
        acc[cb][1] = MFMA(xf[1][s], wsk[cb][s], acc[cb][1]);
      }
    #pragma unroll
    for (int cb = 0; cb < 4; ++cb)
      #pragma unroll
      for (int th = 0; th < 2; ++th)
        #pragma unroll
        for (int q = 0; q < 4; ++q) acc[cb][th][q] += s2f(hv[cb][th][q]);
    // hs2 -> LDS [pos][ch] (scalar transpose-writes)
    #pragma unroll
    for (int cb = 0; cb < 4; ++cb)
      #pragma unroll
      for (int th = 0; th < 2; ++th)
        #pragma unroll
        for (int q = 0; q < 4; ++q)
          hs2L[wv][th*16 + 4*g + q][cb*16 + r] = f2bs(acc[cb][th][q]);
    short8 hf[2][2];
    #pragma unroll
    for (int th = 0; th < 2; ++th)
      #pragma unroll
      for (int s = 0; s < 2; ++s)
        hf[th][s] = *(const short8*)&hs2L[wv][th*16 + r][s*32 + g*8];

    // u1 (transposed, BN folded): C[row=ch(4g+q)][col=pos(r)]
    f32x4 a1[4][2];
    #pragma unroll
    for (int cb = 0; cb < 4; ++cb) { a1[cb][0] = b1c[cb]; a1[cb][1] = b1c[cb]; }
    #pragma unroll
    for (int cb = 0; cb < 4; ++cb)
      #pragma unroll
      for (int s = 0; s < 2; ++s) {
        a1[cb][0] = MFMA(w1f[cb][s], hf[0][s], a1[cb][0]);
        a1[cb][1] = MFMA(w1f[cb][s], hf[1][s], a1[cb][1]);
      }
    #pragma unroll
    for (int cb = 0; cb < 4; ++cb)
      #pragma unroll
      for (int th = 0; th < 2; ++th) {
        short4v v;
        #pragma unroll
        for (int q = 0; q < 4; ++q) v[q] = f2bs(fmaxf(a1[cb][th][q], 0.f));
        *(short4v*)&u1L[wv][th*16 + r][cb*16 + 4*g] = v;
      }
    short8 uf[2][2];
    #pragma unroll
    for (int th = 0; th < 2; ++th)
      #pragma unroll
      for (int s = 0; s < 2; ++s)
        uf[th][s] = *(const short8*)&u1L[wv][th*16 + r][s*32 + g*8];

    // u2 (transposed, BN folded) + residual -> out
    f32x4 a2[4][2];
    #pragma unroll
    for (int cb = 0; cb < 4; ++cb) { a2[cb][0] = b2c[cb]; a2[cb][1] = b2c[cb]; }
    #pragma unroll
    for (int cb = 0; cb < 4; ++cb)
      #pragma unroll
      for (int s = 0; s < 2; ++s) {
        a2[cb][0] = MFMA(w2f[cb][s], uf[0][s], a2[cb][0]);
        a2[cb][1] = MFMA(w2f[cb][s], uf[1][s], a2[cb][1]);
      }
    #pragma unroll
    for (int cb = 0; cb < 4; ++cb)
      #pragma unroll
      for (int th = 0; th < 2; ++th) {
        short4v hres = *(const short4v*)&hs2L[wv][th*16 + r][cb*16 + 4*g];
        f32x4 res;
        #pragma unroll
        for (int q = 0; q < 4; ++q)
          res[q] = fmaxf(a2[cb][th][q], 0.f) + s2f(hres[q]);
        *(f32x4*)(out + (pb + th*16 + r)*64 + cb*16 + 4*g) = res;
      }
  }
}

// ---------------------------------------------------------------------------
extern "C" void kernel_launch(void* const* d_in, const int* in_sizes, int n_in,
                              void* d_out, int out_size, void* d_ws, size_t ws_size,
                              hipStream_t stream) {
  const float* x     = (const float*)d_in[0];
  const float* w_m1  = (const float*)d_in[1];
  const float* b_m1  = (const float*)d_in[2];
  const float* w_m2  = (const float*)d_in[3];
  const float* b_m2  = (const float*)d_in[4];
  const float* Wskip = (const float*)d_in[5];
  const float* bskip = (const float*)d_in[6];
  const float* Wu1   = (const float*)d_in[7];
  const float* bu1   = (const float*)d_in[8];
  const float* g1    = (const float*)d_in[9];
  const float* be1   = (const float*)d_in[10];
  const float* rm1   = (const float*)d_in[11];
  const float* rv1   = (const float*)d_in[12];
  const float* Wu2   = (const float*)d_in[13];
  const float* bu2   = (const float*)d_in[14];
  const float* g2    = (const float*)d_in[15];
  const float* be2   = (const float*)d_in[16];
  const float* rm2   = (const float*)d_in[17];
  const float* rv2   = (const float*)d_in[18];
  float* out = (float*)d_out;

  bf16* m1t = (bf16*)d_ws;
  bf16* m2t = m1t + (size_t)64 * NT;
  bf16* ht  = m1t;   // safe alias: each k2 block overwrites only its own region

  k1_mlp<<<1088, 256, 0, stream>>>(x, w_m1, b_m1, w_m2, b_m2, m1t, m2t);

  k2_spatial<32><<<128*64, 256, 0, stream>>>(m1t, m2t, ht, 0);
  k2_spatial<48><<< 64*64, 256, 0, stream>>>(m1t, m2t, ht, 131072);
  k2_spatial<64><<< 32*64, 256, 0, stream>>>(m1t, m2t, ht, 278528);
  k2_spatial<96><<< 16*64, 256, 0, stream>>>(m1t, m2t, ht, 409600);

  k3_update<<<1088, 256, 0, stream>>>(x, ht, Wskip, bskip,
                                      Wu1, bu1, g1, be1, rm1, rv1,
                                      Wu2, bu2, g2, be2, rm2, rv2, out);
}